// Round 11
// baseline (87.922 us; speedup 1.0000x reference)
//
#include <hip/hip_runtime.h>
#include <stdint.h>

typedef __attribute__((ext_vector_type(4)))  int   i32x4;
typedef __attribute__((ext_vector_type(8)))  int   i32x8;
typedef __attribute__((ext_vector_type(16))) float f32x16;

#define NB 8
#define NC 1024
#define NHW 3136
#define ROWB8 3200        // fp8 row stride: 3136 data + 64 zero pad = 25*128

__device__ inline float sq4(float4 v){
  return fmaf(v.x,v.x, fmaf(v.y,v.y, fmaf(v.z,v.z, v.w*v.w)));
}

__device__ __forceinline__ void load_lds16(const void* g, void* l){
  __builtin_amdgcn_global_load_lds(
      (const __attribute__((address_space(1))) unsigned int*)g,
      (__attribute__((address_space(3))) unsigned int*)l,
      16, 0, 0);
}

// MX-scaled fp8 MFMA, both formats e4m3 (fmt=0), all block scales = 2^0.
__device__ __forceinline__ f32x16 MFS(i32x8 a, i32x8 b, f32x16 c){
  return __builtin_amdgcn_mfma_scale_f32_32x32x64_f8f6f4(
      a, b, c, 0, 0, 0, 0x7F7F7F7F, 0, 0x7F7F7F7F);
}

__device__ __forceinline__ i32x8 rdfrag(const char* base, int cLo, int cHi){
  i32x4 lo = *(const i32x4*)(base + cLo);
  i32x4 hi = *(const i32x4*)(base + cHi);
  return __builtin_shufflevector(lo, hi, 0,1,2,3,4,5,6,7);
}

__device__ __forceinline__ int cvt4(float4 v, float s){
  int pk = __builtin_amdgcn_cvt_pk_fp8_f32(v.x*s, v.y*s, 0,  0);
  pk     = __builtin_amdgcn_cvt_pk_fp8_f32(v.z*s, v.w*s, pk, 1);
  return pk;
}

// ---------------- k_norm: LDS-staged via global_load_lds DMA ---------------
// (unchanged from r10 -- best/lowest-variance of 4 structures tried; at
// ~77% of the pure-copy BW ceiling for a read+reduce+cvt+write kernel.)
__global__ __launch_bounds__(256, 8) void k_norm(const float* __restrict__ s,
                                                 const float* __restrict__ t,
                                                 char* __restrict__ Sn,
                                                 char* __restrict__ Tn,
                                                 float* __restrict__ accbuf){
  __shared__ float4 buf[784];          // 12544 B
  __shared__ float red[4];
  const int g   = blockIdx.x;          // one row per block, 16384 rows
  const int tid = threadIdx.x;
  if (g == 0 && tid == 0){ accbuf[0] = 0.f; accbuf[1] = 0.f; }
  const bool isS = (g < 8192);
  const int r = isS ? g : g - 8192;
  const float* src = (isS ? s : t) + (size_t)r * NHW;
  char*        dst = (isS ? Sn : Tn) + (size_t)r * ROWB8;

  // DMA row -> LDS (no VGPR round-trip)
  {
    const char* gp = (const char*)src + tid*16;
    char*       lp = (char*)buf + tid*16;     // wave-uniform base + lane*16
    load_lds16(gp,         lp);
    load_lds16(gp +  4096, lp +  4096);
    load_lds16(gp +  8192, lp +  8192);
    if (tid < 16) load_lds16(gp + 12288, lp + 12288);
  }
  asm volatile("s_waitcnt vmcnt(0)" ::: "memory");
  __syncthreads();

  // reduce from LDS
  float ssq = sq4(buf[tid]) + sq4(buf[tid+256]) + sq4(buf[tid+512]);
  if (tid < 16) ssq += sq4(buf[tid+768]);
  #pragma unroll
  for (int off = 32; off; off >>= 1) ssq += __shfl_down(ssq, off);
  if ((tid & 63) == 0) red[tid>>6] = ssq;
  __syncthreads();
  const float inv = 32.0f / fmaxf(sqrtf(red[0]+red[1]+red[2]+red[3]), 1e-12f);

  // cvt+store; re-read is from LDS (cheap), not L2/HBM
  *(int*)(dst + 4*tid)        = cvt4(buf[tid],     inv);
  *(int*)(dst + 4*tid + 1024) = cvt4(buf[tid+256], inv);
  *(int*)(dst + 4*tid + 2048) = cvt4(buf[tid+512], inv);
  if (tid < 16)      *(int*)(dst + 3072 + 4*tid) = cvt4(buf[tid+768], inv);
  else if (tid < 20) *(int4*)(dst + 3136 + 16*(tid-16)) = make_int4(0,0,0,0);
}

// ---------------- 256x256 4-phase MX-fp8 GEMM, fused squared-sum -----------
// r4's verified 8-phase schedule with quadrant pairs MERGED (fp8's 4-MFMA
// quadrant is ~137 cyc of matrix work vs ~450 cyc phase overhead -> the
// 8-phase was barrier-bound). 4 phases per 2 K-tiles: 8 MFMA + 16/8 ds_reads
// each; barrier count halved. vmcnt ledger re-derived (see round notes):
// prologue VM6 drains t0; P1-VM6 drains t1 (14->6); P3-VM6 drains t2;
// epilogue junk t3-clamp targets buf1 only. Per-acc MFMA chain order
// unchanged -> bitwise-identical result to r4.

#define BAR   __builtin_amdgcn_s_barrier()
#define LGKM0 asm volatile("s_waitcnt lgkmcnt(0)" ::: "memory")
#define LGKM8 asm volatile("s_waitcnt lgkmcnt(8)" ::: "memory")
#define VM6   asm volatile("s_waitcnt vmcnt(6)" ::: "memory")
#define SB0   __builtin_amdgcn_sched_barrier(0)
#define PRIO1 __builtin_amdgcn_s_setprio(1)
#define PRIO0 __builtin_amdgcn_s_setprio(0)

#define ISSUE(MAT, D, H, KT) do{ \
  const char* _g = ((MAT)? gB : gA) + (KT)*128 + (H)*(128*ROWB8); \
  char* _d = ldsw + (D)*65536 + (MAT)*32768 + (H)*16384; \
  load_lds16(_g,              _d); \
  load_lds16(_g + 64*ROWB8,   _d + 8192); \
}while(0)

#define RDA(D, MH) do{ \
  const char* _a = aRow + (D) + (MH)*8192; \
  af[0][0] = rdfrag(_a,        c00, c01); \
  af[0][1] = rdfrag(_a,        c10, c11); \
  af[1][0] = rdfrag(_a + 4096, c00, c01); \
  af[1][1] = rdfrag(_a + 4096, c10, c11); \
}while(0)

#define RDB(D, NH) do{ \
  const char* _b = bRow + (D) + (NH)*4096; \
  bf[NH][0] = rdfrag(_b, c00, c01); \
  bf[NH][1] = rdfrag(_b, c10, c11); \
}while(0)

#define MMQ(MH, NH) do{ \
  acc[((MH)*2+0)*2+(NH)] = MFS(af[0][0], bf[NH][0], acc[((MH)*2+0)*2+(NH)]); \
  acc[((MH)*2+1)*2+(NH)] = MFS(af[1][0], bf[NH][0], acc[((MH)*2+1)*2+(NH)]); \
  acc[((MH)*2+0)*2+(NH)] = MFS(af[0][1], bf[NH][1], acc[((MH)*2+0)*2+(NH)]); \
  acc[((MH)*2+1)*2+(NH)] = MFS(af[1][1], bf[NH][1], acc[((MH)*2+1)*2+(NH)]); \
}while(0)

__global__ __launch_bounds__(512,2) void k_gemm(const char* __restrict__ Sn,
                                                const char* __restrict__ Tn,
                                                float* __restrict__ accbuf){
  __shared__ char lds[131072];
  const int tid = threadIdx.x;
  const int l   = tid & 63;
  const int w   = tid >> 6;
  const int wr  = w >> 2;      // 0..1
  const int wc  = w & 3;       // 0..3

  const int b   = blockIdx.x & 7;    // batch -> XCD (208 = 8*26)
  const int idx = blockIdx.x >> 3;   // 0..25
  int tm, tn, which; float wgt;
  if (idx < 16){ which = 1; tm = idx >> 2; tn = idx & 3; wgt = 1.f; }
  else {
    int e = idx - 16; which = 0;
    if      (e < 4){ tm = 0; tn = e;   }
    else if (e < 7){ tm = 1; tn = e-3; }
    else if (e < 9){ tm = 2; tn = e-5; }
    else           { tm = 3; tn = 3;   }
    wgt = (tm == tn) ? 1.f : 2.f;
  }
  const char* Ab = (which ? Tn : Sn) + (size_t)b*(NC*ROWB8) + (size_t)tm*(256*ROWB8);
  const char* Bb = Sn                + (size_t)b*(NC*ROWB8) + (size_t)tn*(256*ROWB8);

  const int scol = ((l & 7) << 4) ^ ((l >> 3) << 4);
  const char* gA = Ab + (8*w + (l >> 3))*ROWB8 + scol;
  const char* gB = Bb + (8*w + (l >> 3))*ROWB8 + scol;
  char* ldsw = lds + w*1024;

  const int swz = (l & 7) << 4;
  const int cg  = 32*(l >> 5);
  const int c00 = ( cg           ) ^ swz;
  const int c01 = ( cg | 16      ) ^ swz;
  const int c10 = ( cg | 64      ) ^ swz;
  const int c11 = ( cg | 64 | 16 ) ^ swz;
  const char* aRow = lds +         (wr*128 + (l & 31))*128;
  const char* bRow = lds + 32768 + (wc*64  + (l & 31))*128;

  i32x8 af[2][2], bf[2][2];
  f32x16 acc[8];
  #pragma unroll
  for (int i = 0; i < 8; i++) acc[i] = (f32x16){};

  ISSUE(1,0,0,0); ISSUE(1,0,1,0); ISSUE(0,0,0,0); ISSUE(0,0,1,0);
  ISSUE(1,1,0,1); ISSUE(1,1,1,1); ISSUE(0,1,0,1);
  VM6; BAR;   // oldest 8 loads (= all of t0) landed

  for (int i = 0; i < 12; i++){
    const int t1 = 2*i + 1;
    const int t2 = 2*i + 2;
    int t3 = 2*i + 3; if (t3 > 24) t3 = 24;   // clamp keeps vmcnt uniform

    // P0: tile 2i (buf0), MH=0 -- 16 reads, 8 MFMA
    RDA(0,0); RDB(0,0); RDB(0,1);
    ISSUE(0,1,1,t1);
    LGKM8; BAR; LGKM0; SB0; PRIO1; MMQ(0,0); MMQ(0,1); PRIO0; BAR;
    // P1: tile 2i, MH=1 -- 8 reads, 8 MFMA; counted drain for t1
    RDA(0,1);
    ISSUE(1,0,0,t2); ISSUE(1,0,1,t2); ISSUE(0,0,0,t2);
    BAR; LGKM0; SB0; PRIO1; MMQ(1,0); MMQ(1,1); PRIO0; VM6; BAR;

    // P2: tile 2i+1 (buf1), MH=0
    RDA(65536,0); RDB(65536,0); RDB(65536,1);
    ISSUE(0,0,1,t2);
    LGKM8; BAR; LGKM0; SB0; PRIO1; MMQ(0,0); MMQ(0,1); PRIO0; BAR;
    // P3: tile 2i+1, MH=1; counted drain for t2
    RDA(65536,1);
    ISSUE(1,1,0,t3); ISSUE(1,1,1,t3); ISSUE(0,1,0,t3);
    BAR; LGKM0; SB0; PRIO1; MMQ(1,0); MMQ(1,1); PRIO0; VM6; BAR;
  }

  // Epilogue: tile 24 (buf0), fully landed by final VM6+BAR (junk t3-clamp
  // loads are the 6 newest and target buf1 only).
  RDA(0,0); RDB(0,0); RDB(0,1);
  MMQ(0,0); MMQ(0,1);
  RDA(0,1);
  MMQ(1,0); MMQ(1,1);

  // Fused reduction: sum of squares of the 256x256 tile (layout-free).
  float p = 0.f;
  #pragma unroll
  for (int f = 0; f < 8; f++)
    #pragma unroll
    for (int e = 0; e < 16; e++)
      p = fmaf(acc[f][e], acc[f][e], p);
  #pragma unroll
  for (int off = 32; off; off >>= 1) p += __shfl_down(p, off);
  __syncthreads();
  float* red = (float*)lds;
  if (l == 0) red[w] = p;
  __syncthreads();
  if (tid == 0){
    float sum = red[0]+red[1]+red[2]+red[3]+red[4]+red[5]+red[6]+red[7];
    atomicAdd(&accbuf[which], wgt * sum);
  }
}

__global__ void k_fin(const float* __restrict__ acc, float* __restrict__ out){
  // / (8*1024*1024) and / 2^20 (both operands pre-scaled by 2^5)
  out[0] = (acc[0] - 2.0f*acc[1]) * 1.1368683772161603e-13f;   // 2^-43
}

extern "C" void kernel_launch(void* const* d_in, const int* in_sizes, int n_in,
                              void* d_out, int out_size, void* d_ws, size_t ws_size,
                              hipStream_t stream){
  const float* fs = (const float*)d_in[0];
  const float* ft = (const float*)d_in[1];
  float* out = (float*)d_out;
  float* accbuf = (float*)d_ws;
  char* Sn = (char*)d_ws + 256;
  char* Tn = Sn + (size_t)NB*NC*ROWB8;   // 2 x 26.2 MB of ws

  k_norm<<<dim3(16384), dim3(256), 0, stream>>>(fs, ft, Sn, Tn, accbuf);
  k_gemm<<<dim3(208), dim3(512), 0, stream>>>(Sn, Tn, accbuf);
  k_fin<<<1, 1, 0, stream>>>(accbuf, out);
}